// Round 6
// baseline (534.338 us; speedup 1.0000x reference)
//
#include <hip/hip_runtime.h>
#include <cstdint>

#define DEVI __device__ __forceinline__

typedef __bf16 bf16x8_t __attribute__((ext_vector_type(8)));
typedef float f32x4_t __attribute__((ext_vector_type(4)));

typedef const __attribute__((address_space(1))) unsigned int* gas_t;
typedef __attribute__((address_space(3))) unsigned int* las_t;

// async global->LDS, 16B per lane, dst = wave-uniform base (+lane*16 by HW)
DEVI void glds16(const void* g, void* l) {
  __builtin_amdgcn_global_load_lds((gas_t)g, (las_t)l, 16, 0, 0);
}

DEVI uint16_t f2b(float f) {  // fp32 -> bf16 RNE
  uint32_t u = __builtin_bit_cast(uint32_t, f);
  u += 0x7fffu + ((u >> 16) & 1u);
  return (uint16_t)(u >> 16);
}

// opaque LDS b128 read: invisible to SIInsertWaitcnts => no auto vmcnt(0)
// drain against in-flight global_load_lds. Caller MUST wait lgkmcnt +
// sched_barrier(0) before consuming (rule 18).
template <int IMM>
DEVI f32x4_t ldsr(uint32_t addr) {
  f32x4_t r;
  if constexpr (IMM == 0)
    asm volatile("ds_read_b128 %0, %1" : "=v"(r) : "v"(addr));
  else if constexpr (IMM == 2048)
    asm volatile("ds_read_b128 %0, %1 offset:2048" : "=v"(r) : "v"(addr));
  else if constexpr (IMM == 4096)
    asm volatile("ds_read_b128 %0, %1 offset:4096" : "=v"(r) : "v"(addr));
  else
    asm volatile("ds_read_b128 %0, %1 offset:6144" : "=v"(r) : "v"(addr));
  return r;
}

// meta layout (ints): [0..7] counts, [8..16] offsets(9), [17..24] fill,
// [25] nTiles128, [32..103] tileExpert, [104..175] tilePos0, [176..247] tileValidEnd
static constexpr int MAXT = 72;

// ---------------- gate: logits + top2 + softmax ----------------
__global__ __launch_bounds__(256) void moe_gate(const float* __restrict__ x,
    const float* __restrict__ Wg, const float* __restrict__ bg,
    int* __restrict__ gidx, float* __restrict__ gw) {
  const int lane = threadIdx.x & 63;
  const int b = blockIdx.x * 4 + (threadIdx.x >> 6);
  float acc[8];
#pragma unroll
  for (int e = 0; e < 8; ++e) acc[e] = 0.f;
  const float* xr = x + (size_t)b * 1024;
#pragma unroll
  for (int it = 0; it < 4; ++it) {
    const int d0 = it * 256 + lane * 4;
    float4 xv = *(const float4*)(xr + d0);
    float xs[4] = {xv.x, xv.y, xv.z, xv.w};
#pragma unroll
    for (int q = 0; q < 4; ++q) {
      const float4* wrow = (const float4*)(Wg + (size_t)(d0 + q) * 8);
      float4 wa = wrow[0], wb = wrow[1];
      acc[0] += xs[q] * wa.x; acc[1] += xs[q] * wa.y;
      acc[2] += xs[q] * wa.z; acc[3] += xs[q] * wa.w;
      acc[4] += xs[q] * wb.x; acc[5] += xs[q] * wb.y;
      acc[6] += xs[q] * wb.z; acc[7] += xs[q] * wb.w;
    }
  }
#pragma unroll
  for (int off = 32; off; off >>= 1)
#pragma unroll
    for (int e = 0; e < 8; ++e) acc[e] += __shfl_xor(acc[e], off, 64);
  if (lane == 0) {
    float l[8];
#pragma unroll
    for (int e = 0; e < 8; ++e) l[e] = acc[e] + bg[e];
    int i0 = 0;
#pragma unroll
    for (int e = 1; e < 8; ++e) if (l[e] > l[i0]) i0 = e;   // strict > : matches top_k tie rule
    int i1 = (i0 == 0) ? 1 : 0;
#pragma unroll
    for (int e = 0; e < 8; ++e) if (e != i0 && l[e] > l[i1]) i1 = e;
    float ex = expf(l[i1] - l[i0]);
    float s = 1.f + ex;
    gidx[2 * b] = i0; gidx[2 * b + 1] = i1;
    gw[2 * b] = 1.f / s; gw[2 * b + 1] = ex / s;
  }
}

// ---------------- scan: counts -> offsets -> tile table ----------------
__global__ __launch_bounds__(256) void moe_scan(const int* __restrict__ gidx,
                                                int* __restrict__ meta) {
  __shared__ int cnt[8];
  if (threadIdx.x < 8) cnt[threadIdx.x] = 0;
  __syncthreads();
  int loc[8] = {0, 0, 0, 0, 0, 0, 0, 0};
  for (int i = threadIdx.x; i < 8192; i += 256) {
    int e = gidx[i];
#pragma unroll
    for (int q = 0; q < 8; ++q) loc[q] += (e == q) ? 1 : 0;
  }
#pragma unroll
  for (int q = 0; q < 8; ++q) atomicAdd(&cnt[q], loc[q]);
  __syncthreads();
  if (threadIdx.x == 0) {
    int off = 0, t = 0;
    for (int e = 0; e < 8; ++e) {
      int c = cnt[e];
      meta[e] = c;
      meta[8 + e] = off;
      meta[17 + e] = 0;  // fill counters
      int nt = (c + 127) >> 7;
      for (int mt = 0; mt < nt; ++mt) {
        meta[32 + t] = e;
        meta[104 + t] = off + mt * 128;
        meta[176 + t] = off + c;
        ++t;
      }
      off += c;
    }
    meta[16] = off;
    meta[25] = t;
  }
}

// ---------------- scatter assignments into expert-sorted lists ----------------
__global__ __launch_bounds__(256) void moe_scatter(const int* __restrict__ gidx,
    const float* __restrict__ gw, int* __restrict__ meta,
    int* __restrict__ row_index, float* __restrict__ row_w) {
  int i = blockIdx.x * 256 + threadIdx.x;  // 8192 assignments
  int e = gidx[i];
  int pos = meta[8 + e] + atomicAdd(&meta[17 + e], 1);
  row_index[pos] = i >> 1;
  row_w[pos] = gw[i];
}

// ---------------- x fp32 -> bf16 ----------------
__global__ __launch_bounds__(256) void moe_cvtx(const float* __restrict__ x,
                                                uint16_t* __restrict__ xb) {
  size_t i = ((size_t)blockIdx.x * 256 + threadIdx.x) * 4;
  float4 v = *(const float4*)(x + i);
  uint64_t pk = (uint64_t)f2b(v.x) | ((uint64_t)f2b(v.y) << 16) |
                ((uint64_t)f2b(v.z) << 32) | ((uint64_t)f2b(v.w) << 48);
  *(uint64_t*)(xb + i) = pk;
}

// ---------------- W [E][K][N] fp32 -> Wt [E][N][K] bf16 ----------------
__global__ __launch_bounds__(256) void moe_transpose(const float* __restrict__ in,
                                                     uint16_t* __restrict__ outp,
                                                     int K, int N) {
  __shared__ uint16_t t[64][72];
  const int e = blockIdx.z;
  const int k0 = blockIdx.y * 64, n0 = blockIdx.x * 64;
  const int r = threadIdx.x >> 2;          // 0..63
  const int c0 = (threadIdx.x & 3) * 16;   // 0,16,32,48
  const float* src = in + ((size_t)e * K + k0 + r) * N + n0 + c0;
#pragma unroll
  for (int q = 0; q < 4; ++q) {
    float4 v = *(const float4*)(src + q * 4);
    uint64_t pk = (uint64_t)f2b(v.x) | ((uint64_t)f2b(v.y) << 16) |
                  ((uint64_t)f2b(v.z) << 32) | ((uint64_t)f2b(v.w) << 48);
    *(uint64_t*)&t[r][c0 + q * 4] = pk;
  }
  __syncthreads();
  alignas(16) uint16_t buf[16];
#pragma unroll
  for (int j = 0; j < 16; ++j) buf[j] = t[c0 + j][r];
  uint16_t* dst = outp + ((size_t)e * N + n0 + r) * K + k0 + c0;
  *(uint4*)dst = *(const uint4*)&buf[0];
  *(uint4*)(dst + 8) = *(const uint4*)&buf[8];
}

// ======== GEMM r6: 128x256 tile, BK=64, 8 waves (2Mx4N), 1 block/CU ========
// Double-buffered LDS: buf stride 64KB (A [128][64] @+0 16KB, B [256][64]
// @+16KB 32KB; 16KB pad). Per K-tile per wave: 6 glds16 (issued first),
// 16 opaque ds_read_b128 in two ks-groups, counted lgkmcnt(8)/(0), 2x16 MFMA
// with setprio, then vmcnt(0)+s_barrier once per K-tile. Per-block MFMA wall
// per K-tile ~1240cy > HBM latency => double buffer covers.
// Swizzle: LDS slot (row,s) holds global k-chunk s^(row&7); read slot =
// gc^(lane&7) (row&7==lane&7; ks1 addr = ks0 addr XOR 64).
// Grid order: nb_lo(4) inner, ty(72), then {s-group | splitK}.
// MODE 1: h[pos] = relu(gather(x)[pos] @ W1t[e]^T + b1[e])
// MODE 2: out[rix[pos]] += rw[pos] * (h[pos] @ W2t[e]^T + b2[e])
template <int KD, int ND, int MODE, int KSL, int NBQ>
__global__ __launch_bounds__(512, 2) void moe_gemm(
    const uint16_t* __restrict__ Am, const uint16_t* __restrict__ Bt,
    const float* __restrict__ bias, const int* __restrict__ meta,
    const int* __restrict__ row_index, const float* __restrict__ row_w,
    uint16_t* __restrict__ hout, float* __restrict__ out) {
  constexpr int KSLEN = KD / KSL;
  constexpr int NIT = KSLEN / 64;
  extern __shared__ uint16_t lds[];

  // bijective XCD chunk swizzle on flat id
  const int nwg = gridDim.x;
  const int orig = blockIdx.x;
  const int q8 = nwg >> 3, r8 = nwg & 7, xcd = orig & 7, loc = orig >> 3;
  int wg = (xcd < r8 ? xcd * (q8 + 1) : r8 * (q8 + 1) + (xcd - r8) * q8) + loc;
  const int nb_lo = wg & 3; wg >>= 2;
  const int ty = wg % MAXT; wg /= MAXT;
  const int sgrp = wg % NBQ;
  const int ks = wg / NBQ;
  const int nb = sgrp * 4 + nb_lo;
  if (ty >= meta[25]) return;
  const int e = meta[32 + ty];
  const int pos0 = meta[104 + ty];
  const int vend = meta[176 + ty];
  const int k0 = ks * KSLEN;

  const int tid = threadIdx.x;
  const int lane = tid & 63;
  const int w = tid >> 6;          // 0..7
  const int wr = w >> 2, wc = w & 3;

  // staging source offsets. A: chunks c=(w*2+i)*64+lane over [0,1024);
  // B: c=(w*4+i)*64+lane over [0,2048). row=c>>3, stored slot=c&7 holds
  // global chunk (c&7)^(row&7).
  size_t aoff[2], boff[4];
#pragma unroll
  for (int i = 0; i < 2; ++i) {
    int c = (w * 2 + i) * 64 + lane;
    int row = c >> 3;
    int gc = (c & 7) ^ (row & 7);
    int pos = pos0 + row; if (pos > 8191) pos = 8191;
    int ar = (MODE == 1) ? row_index[pos] : pos;
    aoff[i] = ((size_t)ar * KD + k0 + gc * 8) * 2;
  }
#pragma unroll
  for (int i = 0; i < 4; ++i) {
    int c = (w * 4 + i) * 64 + lane;
    int row = c >> 3;
    int gc = (c & 7) ^ (row & 7);
    boff[i] = (((size_t)e * ND + (size_t)nb * 256 + row) * KD + k0 + gc * 8) * 2;
  }
  const char* Ag = (const char*)Am;
  const char* Bg = (const char*)Bt;

  auto stage = [&](int kt, int buf) {
    uint16_t* base = lds + buf * 32768;
#pragma unroll
    for (int i = 0; i < 2; ++i)
      glds16(Ag + aoff[i] + (size_t)kt * 128, base + (w * 2 + i) * 512);
#pragma unroll
    for (int i = 0; i < 4; ++i)
      glds16(Bg + boff[i] + (size_t)kt * 128, base + 8192 + (w * 4 + i) * 512);
  };

  f32x4_t acc[4][4];
  f32x4_t z; z[0] = 0.f; z[1] = 0.f; z[2] = 0.f; z[3] = 0.f;
#pragma unroll
  for (int m = 0; m < 4; ++m)
#pragma unroll
    for (int n = 0; n < 4; ++n) acc[m][n] = z;

  // frag read base addrs (bytes). row=base+(lane&15): row&7 = lane&7 =>
  // slot term invariant across m/n. ks0 slot = (lane>>4)^(lane&7).
  const uint32_t lbase = (uint32_t)(size_t)&lds[0];
  const uint32_t slot0 = (uint32_t)(((lane >> 4) ^ (lane & 7)) & 7);
  const uint32_t aRd = lbase + (uint32_t)((wr * 64 + (lane & 15)) * 128) + slot0 * 16;
  const uint32_t bRd = lbase + 16384 + (uint32_t)((wc * 64 + (lane & 15)) * 128) + slot0 * 16;

  stage(0, 0);
  asm volatile("s_waitcnt vmcnt(0)" ::: "memory");
  __builtin_amdgcn_s_barrier();

  for (int t = 0; t < NIT; ++t) {
    int tc = t + 1; if (tc > NIT - 1) tc = NIT - 1;  // tail dup, harmless
    stage(tc, (t + 1) & 1);

    const uint32_t bo = (t & 1) ? 65536u : 0u;
    const uint32_t aA = aRd + bo, bA = bRd + bo;
    const uint32_t aB = aA ^ 64u, bB = bA ^ 64u;   // ks1: slot ^= 4

    f32x4_t xa0[4], yb0[4], xa1[4], yb1[4];
    xa0[0] = ldsr<0>(aA); xa0[1] = ldsr<2048>(aA); xa0[2] = ldsr<4096>(aA); xa0[3] = ldsr<6144>(aA);
    yb0[0] = ldsr<0>(bA); yb0[1] = ldsr<2048>(bA); yb0[2] = ldsr<4096>(bA); yb0[3] = ldsr<6144>(bA);
    xa1[0] = ldsr<0>(aB); xa1[1] = ldsr<2048>(aB); xa1[2] = ldsr<4096>(aB); xa1[3] = ldsr<6144>(aB);
    yb1[0] = ldsr<0>(bB); yb1[1] = ldsr<2048>(bB); yb1[2] = ldsr<4096>(bB); yb1[3] = ldsr<6144>(bB);

    asm volatile("s_waitcnt lgkmcnt(8)" ::: "memory");  // ks0 group done
    __builtin_amdgcn_sched_barrier(0);
    __builtin_amdgcn_s_setprio(1);
#pragma unroll
    for (int m = 0; m < 4; ++m)
#pragma unroll
      for (int n = 0; n < 4; ++n)
        acc[m][n] = __builtin_amdgcn_mfma_f32_16x16x32_bf16(
            __builtin_bit_cast(bf16x8_t, xa0[m]), __builtin_bit_cast(bf16x8_t, yb0[n]),
            acc[m][n], 0, 0, 0);
    __builtin_amdgcn_s_setprio(0);

    asm volatile("s_waitcnt lgkmcnt(0)" ::: "memory");  // ks1 group done
    __builtin_amdgcn_sched_barrier(0);
    __builtin_amdgcn_s_setprio(1);
#pragma unroll
    for (int m = 0; m < 4; ++m)
#pragma unroll
      for (int n = 0; n < 4; ++n)
        acc[m][n] = __builtin_amdgcn_mfma_f32_16x16x32_bf16(
            __builtin_bit_cast(bf16x8_t, xa1[m]), __builtin_bit_cast(bf16x8_t, yb1[n]),
            acc[m][n], 0, 0, 0);
    __builtin_amdgcn_s_setprio(0);

    asm volatile("s_waitcnt vmcnt(0)" ::: "memory");  // next tile fully staged
    __builtin_amdgcn_s_barrier();
  }

  // epilogue: C/D mapping col=lane&15, row=(lane>>4)*4+i
  const int cb = nb * 256 + wc * 64;
  if constexpr (MODE == 1) {
#pragma unroll
    for (int m = 0; m < 4; ++m) {
      int pr = pos0 + wr * 64 + m * 16 + ((lane >> 4) << 2);
#pragma unroll
      for (int i = 0; i < 4; ++i) {
        int pos = pr + i;
        if (pos < vend) {
#pragma unroll
          for (int n = 0; n < 4; ++n) {
            int col = cb + n * 16 + (lane & 15);
            float v = acc[m][n][i] + bias[e * ND + col];
            v = fmaxf(v, 0.f);
            hout[(size_t)pos * ND + col] = f2b(v);
          }
        }
      }
    }
  } else {
#pragma unroll
    for (int m = 0; m < 4; ++m) {
      int pr = pos0 + wr * 64 + m * 16 + ((lane >> 4) << 2);
#pragma unroll
      for (int i = 0; i < 4; ++i) {
        int pos = pr + i;
        if (pos < vend) {
          int bi = row_index[pos];
          float wgt = row_w[pos];
          float* orow = out + (size_t)bi * ND;
#pragma unroll
          for (int n = 0; n < 4; ++n) {
            int col = cb + n * 16 + (lane & 15);
            float bterm = (ks == 0) ? bias[e * ND + col] : 0.f;
            atomicAdd(orow + col, (acc[m][n][i] + bterm) * wgt);
          }
        }
      }
    }
  }
}

extern "C" void kernel_launch(void* const* d_in, const int* in_sizes, int n_in,
                              void* d_out, int out_size, void* d_ws, size_t ws_size,
                              hipStream_t stream) {
  const float* x  = (const float*)d_in[0];   // [4096,1024]
  const float* Wg = (const float*)d_in[1];   // [1024,8]
  const float* bg = (const float*)d_in[2];   // [8]
  const float* W1 = (const float*)d_in[3];   // [8,1024,4096]
  const float* b1 = (const float*)d_in[4];   // [8,4096]
  const float* W2 = (const float*)d_in[5];   // [8,4096,1024]
  const float* b2 = (const float*)d_in[6];   // [8,1024]
  float* out = (float*)d_out;                // [4096,1024]

  char* ws = (char*)d_ws;
  uint16_t* w1t = (uint16_t*)ws; ws += (size_t)8 * 4096 * 1024 * 2;  // [E][H][D] bf16
  uint16_t* w2t = (uint16_t*)ws; ws += (size_t)8 * 1024 * 4096 * 2;  // [E][O][H] bf16
  uint16_t* xb  = (uint16_t*)ws; ws += (size_t)4096 * 1024 * 2;      // [B][D] bf16
  uint16_t* h   = (uint16_t*)ws; ws += (size_t)8192 * 4096 * 2;      // [8192][H] bf16
  int*   gidx = (int*)ws;   ws += 8192 * 4;
  float* gw   = (float*)ws; ws += 8192 * 4;
  int*   rix  = (int*)ws;   ws += 8192 * 4;
  float* rw   = (float*)ws; ws += 8192 * 4;
  int*   meta = (int*)ws;   ws += 4096;

  hipFuncSetAttribute((const void*)moe_gemm<1024, 4096, 1, 1, 4>,
                      hipFuncAttributeMaxDynamicSharedMemorySize, 131072);
  hipFuncSetAttribute((const void*)moe_gemm<4096, 1024, 2, 4, 1>,
                      hipFuncAttributeMaxDynamicSharedMemorySize, 131072);

  hipMemsetAsync(d_out, 0, (size_t)4096 * 1024 * 4, stream);
  moe_cvtx<<<4096, 256, 0, stream>>>(x, xb);
  moe_transpose<<<dim3(4096 / 64, 1024 / 64, 8), 256, 0, stream>>>(W1, w1t, 1024, 4096);
  moe_transpose<<<dim3(1024 / 64, 4096 / 64, 8), 256, 0, stream>>>(W2, w2t, 4096, 1024);
  moe_gate<<<1024, 256, 0, stream>>>(x, Wg, bg, gidx, gw);
  moe_scan<<<1, 256, 0, stream>>>(gidx, meta);
  moe_scatter<<<32, 256, 0, stream>>>(gidx, gw, meta, rix, rw);
  // grid = 4 nb_lo * 72 ty * (NBQ * KSL) = 1152 for both
  moe_gemm<1024, 4096, 1, 1, 4><<<dim3(1152), 512, 131072, stream>>>(
      xb, w1t, b1, meta, rix, rw, h, nullptr);
  moe_gemm<4096, 1024, 2, 4, 1><<<dim3(1152), 512, 131072, stream>>>(
      h, w2t, b2, meta, rix, rw, nullptr, out);
}

// Round 7
// 487.513 us; speedup vs baseline: 1.0960x; 1.0960x over previous
//
#include <hip/hip_runtime.h>
#include <cstdint>

#define DEVI __device__ __forceinline__

typedef __bf16 bf16x8_t __attribute__((ext_vector_type(8)));
typedef float f32x4_t __attribute__((ext_vector_type(4)));

typedef const __attribute__((address_space(1))) unsigned int* gas_t;
typedef __attribute__((address_space(3))) unsigned int* las_t;

// async global->LDS, 16B per lane, dst = wave-uniform base (+lane*16 by HW)
DEVI void glds16(const void* g, void* l) {
  __builtin_amdgcn_global_load_lds((gas_t)g, (las_t)l, 16, 0, 0);
}

DEVI uint16_t f2b(float f) {  // fp32 -> bf16 RNE
  uint32_t u = __builtin_bit_cast(uint32_t, f);
  u += 0x7fffu + ((u >> 16) & 1u);
  return (uint16_t)(u >> 16);
}

// opaque LDS b128 read: invisible to SIInsertWaitcnts => no auto vmcnt(0)
// drain against in-flight global_load_lds. Caller MUST wait lgkmcnt +
// sched_barrier(0) before consuming (rule 18).
template <int IMM>
DEVI f32x4_t ldsr(uint32_t addr) {
  f32x4_t r;
  if constexpr (IMM == 0)
    asm volatile("ds_read_b128 %0, %1" : "=v"(r) : "v"(addr));
  else if constexpr (IMM == 2048)
    asm volatile("ds_read_b128 %0, %1 offset:2048" : "=v"(r) : "v"(addr));
  else if constexpr (IMM == 4096)
    asm volatile("ds_read_b128 %0, %1 offset:4096" : "=v"(r) : "v"(addr));
  else
    asm volatile("ds_read_b128 %0, %1 offset:6144" : "=v"(r) : "v"(addr));
  return r;
}

// meta: [0..7] counts, [8..16] offsets(9), [17..24] fill, [26] nT256,
// [32+t] tileExpert, [80+t] tilePos0, [128+t] tileValidEnd   (t < 40)
static constexpr int MAXT = 40;

// ---------------- gate: logits + top2 + softmax ----------------
__global__ __launch_bounds__(256) void moe_gate(const float* __restrict__ x,
    const float* __restrict__ Wg, const float* __restrict__ bg,
    int* __restrict__ gidx, float* __restrict__ gw) {
  const int lane = threadIdx.x & 63;
  const int b = blockIdx.x * 4 + (threadIdx.x >> 6);
  float acc[8];
#pragma unroll
  for (int e = 0; e < 8; ++e) acc[e] = 0.f;
  const float* xr = x + (size_t)b * 1024;
#pragma unroll
  for (int it = 0; it < 4; ++it) {
    const int d0 = it * 256 + lane * 4;
    float4 xv = *(const float4*)(xr + d0);
    float xs[4] = {xv.x, xv.y, xv.z, xv.w};
#pragma unroll
    for (int q = 0; q < 4; ++q) {
      const float4* wrow = (const float4*)(Wg + (size_t)(d0 + q) * 8);
      float4 wa = wrow[0], wb = wrow[1];
      acc[0] += xs[q] * wa.x; acc[1] += xs[q] * wa.y;
      acc[2] += xs[q] * wa.z; acc[3] += xs[q] * wa.w;
      acc[4] += xs[q] * wb.x; acc[5] += xs[q] * wb.y;
      acc[6] += xs[q] * wb.z; acc[7] += xs[q] * wb.w;
    }
  }
#pragma unroll
  for (int off = 32; off; off >>= 1)
#pragma unroll
    for (int e = 0; e < 8; ++e) acc[e] += __shfl_xor(acc[e], off, 64);
  if (lane == 0) {
    float l[8];
#pragma unroll
    for (int e = 0; e < 8; ++e) l[e] = acc[e] + bg[e];
    int i0 = 0;
#pragma unroll
    for (int e = 1; e < 8; ++e) if (l[e] > l[i0]) i0 = e;   // strict > : matches top_k tie rule
    int i1 = (i0 == 0) ? 1 : 0;
#pragma unroll
    for (int e = 0; e < 8; ++e) if (e != i0 && l[e] > l[i1]) i1 = e;
    float ex = expf(l[i1] - l[i0]);
    float s = 1.f + ex;
    gidx[2 * b] = i0; gidx[2 * b + 1] = i1;
    gw[2 * b] = 1.f / s; gw[2 * b + 1] = ex / s;
  }
}

// ---------------- scan: counts -> offsets -> 256-row tile table ----------------
__global__ __launch_bounds__(256) void moe_scan(const int* __restrict__ gidx,
                                                int* __restrict__ meta) {
  __shared__ int cnt[8];
  if (threadIdx.x < 8) cnt[threadIdx.x] = 0;
  __syncthreads();
  int loc[8] = {0, 0, 0, 0, 0, 0, 0, 0};
  for (int i = threadIdx.x; i < 8192; i += 256) {
    int e = gidx[i];
#pragma unroll
    for (int q = 0; q < 8; ++q) loc[q] += (e == q) ? 1 : 0;
  }
#pragma unroll
  for (int q = 0; q < 8; ++q) atomicAdd(&cnt[q], loc[q]);
  __syncthreads();
  if (threadIdx.x == 0) {
    int off = 0, t = 0;
    for (int e = 0; e < 8; ++e) {
      int c = cnt[e];
      meta[e] = c;
      meta[8 + e] = off;
      meta[17 + e] = 0;  // fill counters
      int nt = (c + 255) >> 8;
      for (int mt = 0; mt < nt; ++mt) {
        meta[32 + t] = e;
        meta[80 + t] = off + mt * 256;
        meta[128 + t] = off + c;
        ++t;
      }
      off += c;
    }
    meta[16] = off;
    meta[26] = t;
  }
}

// ---------------- scatter assignments into expert-sorted lists ----------------
__global__ __launch_bounds__(256) void moe_scatter(const int* __restrict__ gidx,
    const float* __restrict__ gw, int* __restrict__ meta,
    int* __restrict__ row_index, float* __restrict__ row_w) {
  int i = blockIdx.x * 256 + threadIdx.x;  // 8192 assignments
  int e = gidx[i];
  int pos = meta[8 + e] + atomicAdd(&meta[17 + e], 1);
  row_index[pos] = i >> 1;
  row_w[pos] = gw[i];
}

// ---------------- x fp32 -> bf16 ----------------
__global__ __launch_bounds__(256) void moe_cvtx(const float* __restrict__ x,
                                                uint16_t* __restrict__ xb) {
  size_t i = ((size_t)blockIdx.x * 256 + threadIdx.x) * 4;
  float4 v = *(const float4*)(x + i);
  uint64_t pk = (uint64_t)f2b(v.x) | ((uint64_t)f2b(v.y) << 16) |
                ((uint64_t)f2b(v.z) << 32) | ((uint64_t)f2b(v.w) << 48);
  *(uint64_t*)(xb + i) = pk;
}

// ---------------- W [E][K][N] fp32 -> Wt [E][N][K] bf16 ----------------
__global__ __launch_bounds__(256) void moe_transpose(const float* __restrict__ in,
                                                     uint16_t* __restrict__ outp,
                                                     int K, int N) {
  __shared__ uint16_t t[64][72];
  const int e = blockIdx.z;
  const int k0 = blockIdx.y * 64, n0 = blockIdx.x * 64;
  const int r = threadIdx.x >> 2;          // 0..63
  const int c0 = (threadIdx.x & 3) * 16;   // 0,16,32,48
  const float* src = in + ((size_t)e * K + k0 + r) * N + n0 + c0;
#pragma unroll
  for (int q = 0; q < 4; ++q) {
    float4 v = *(const float4*)(src + q * 4);
    uint64_t pk = (uint64_t)f2b(v.x) | ((uint64_t)f2b(v.y) << 16) |
                  ((uint64_t)f2b(v.z) << 32) | ((uint64_t)f2b(v.w) << 48);
    *(uint64_t*)&t[r][c0 + q * 4] = pk;
  }
  __syncthreads();
  alignas(16) uint16_t buf[16];
#pragma unroll
  for (int j = 0; j < 16; ++j) buf[j] = t[c0 + j][r];
  uint16_t* dst = outp + ((size_t)e * N + n0 + r) * K + k0 + c0;
  *(uint4*)dst = *(const uint4*)&buf[0];
  *(uint4*)(dst + 8) = *(const uint4*)&buf[8];
}

// ======== GEMM r7: 256x256, BK=64, 8 waves (2Mx4N), m201 8-phase port ======
// LDS per dbuf (64KB): A tile [256 rows][64k] bytes [0,32KB), B [256][64]
// [32KB,64KB). dbuf1 at +64KB. Half-units (HU, 16KB = 2 glds16): A-h0,A-h1,
// B-h0,B-h1 per K-tile. Iter i computes kt 2i (phases 0-3, dbuf0) and 2i+1
// (phases 4-7, dbuf1). Stage stream lead-5, order [B0,A0,A1,B1]:
//   p0:A0(2i+1) p1:A1(2i+1) p2:B1(2i+1) p3:B0(2i+2) p4:A0(2i+2) p5:A1(2i+2)
//   p6:B1(2i+2) p7:B0(2i+3)   -- every stage >=1 barrier-phase after the
// target region's last read (verified). vmcnt(2) ONLY at p3/p7 (completes
// next K-tile exactly; 1 HU stays in flight). Phase: {ds_reads | 2 glds16}
// -> barrier -> lgkmcnt(0)+sched_barrier -> setprio(1) 16 MFMA setprio(0)
// -> [vmcnt(2)] -> barrier. Swizzle slot=gc^(row&7); ks1 = addr XOR 64.
// MODE 1: h[pos] = relu(gather(xb)[pos] @ W1t[e]^T + b1[e])
// MODE 2: out[rix[pos]] += rw[pos] * (h[pos] @ W2t[e]^T + b2[e]), split-K
template <int Q, int RD, int STREG, int STISA, int STH, int DOVM>
DEVI void phase_fn(uint32_t aBase, uint32_t bBase, f32x4_t (&acc)[8][4],
                   f32x4_t (&breg)[4], const char* Ag, const char* Bg,
                   const uint32_t (&aoffs)[2][2], const uint32_t (&boffs)[2][2],
                   uint32_t kb, char* ldsc, int w) {
  constexpr int mh_ = Q & 1;
  constexpr bool ks_ = (Q >> 1) != 0;
  uint32_t aA = aBase + RD + mh_ * 8192;
  if (ks_) aA ^= 64u;
  f32x4_t a0 = ldsr<0>(aA), a1 = ldsr<2048>(aA), a2 = ldsr<4096>(aA), a3 = ldsr<6144>(aA);
  if constexpr (mh_ == 0) {
    uint32_t bA = bBase + RD;
    if (ks_) bA ^= 64u;
    breg[0] = ldsr<0>(bA); breg[1] = ldsr<2048>(bA);
    breg[2] = ldsr<4096>(bA); breg[3] = ldsr<6144>(bA);
  }
  if constexpr (STISA) {
    glds16(Ag + aoffs[STH][0] + kb, ldsc + STREG + w * 1024);
    glds16(Ag + aoffs[STH][1] + kb, ldsc + STREG + 8192 + w * 1024);
  } else {
    glds16(Bg + boffs[STH][0] + kb, ldsc + STREG + w * 1024);
    glds16(Bg + boffs[STH][1] + kb, ldsc + STREG + 8192 + w * 1024);
  }
  __builtin_amdgcn_s_barrier();
  asm volatile("s_waitcnt lgkmcnt(0)" ::: "memory");
  __builtin_amdgcn_sched_barrier(0);
  __builtin_amdgcn_s_setprio(1);
  f32x4_t aF[4] = {a0, a1, a2, a3};
#pragma unroll
  for (int m = 0; m < 4; ++m)
#pragma unroll
    for (int n = 0; n < 4; ++n)
      acc[mh_ * 4 + m][n] = __builtin_amdgcn_mfma_f32_16x16x32_bf16(
          __builtin_bit_cast(bf16x8_t, aF[m]), __builtin_bit_cast(bf16x8_t, breg[n]),
          acc[mh_ * 4 + m][n], 0, 0, 0);
  __builtin_amdgcn_s_setprio(0);
  if constexpr (DOVM) asm volatile("s_waitcnt vmcnt(2)" ::: "memory");
  __builtin_amdgcn_s_barrier();
}

template <int KD, int ND, int MODE, int KSL>
__global__ __launch_bounds__(512, 2) void moe_gemm8(
    const uint16_t* __restrict__ Am, const uint16_t* __restrict__ Bt,
    const float* __restrict__ bias, const int* __restrict__ meta,
    const int* __restrict__ row_index, const float* __restrict__ row_w,
    uint16_t* __restrict__ hout, float* __restrict__ out) {
  constexpr int NB = ND / 256;
  constexpr int KSLEN = KD / KSL;
  constexpr int NKT = KSLEN / 64;
  constexpr int NIT = NKT / 2;
  extern __shared__ uint16_t lds[];
  char* ldsc = (char*)lds;

  const int nwg = gridDim.x;
  const int orig = blockIdx.x;
  const int q8 = nwg >> 3, r8 = nwg & 7, xcd = orig & 7, loc = orig >> 3;
  int wg = (xcd < r8 ? xcd * (q8 + 1) : r8 * (q8 + 1) + (xcd - r8) * q8) + loc;
  const int nb = wg % NB; wg /= NB;
  const int ks = wg % KSL; wg /= KSL;
  const int ty = wg;
  if (ty >= meta[26]) return;
  const int e = meta[32 + ty];
  const int pos0 = meta[80 + ty];
  const int vend = meta[128 + ty];
  const int k0 = ks * KSLEN;

  const int tid = threadIdx.x;
  const int lane = tid & 63;
  const int w = tid >> 6;           // 0..7
  const int wr = w >> 2, wc = w & 3;

  // staging offsets: HU chunk c = j*512+tid; row-in-half = c>>3; slot=c&7
  // holds global k-chunk gc = (c&7)^((c>>3)&7). k0 folded in; add kt*128 B.
  uint32_t aoffs[2][2], boffs[2][2];
#pragma unroll
  for (int H = 0; H < 2; ++H)
#pragma unroll
    for (int j = 0; j < 2; ++j) {
      int c = j * 512 + tid;
      int row = H * 128 + (c >> 3);
      int gc = (c & 7) ^ ((c >> 3) & 7);
      int pos = pos0 + row; if (pos > 8191) pos = 8191;
      int ar = (MODE == 1) ? row_index[pos] : pos;
      aoffs[H][j] = (uint32_t)ar * (KD * 2) + (uint32_t)(k0 * 2) + gc * 16;
      boffs[H][j] = (uint32_t)(e * ND + nb * 256 + row) * (KD * 2) + (uint32_t)(k0 * 2) + gc * 16;
    }
  const char* Ag = (const char*)Am;
  const char* Bg = (const char*)Bt;

  f32x4_t acc[8][4];
  f32x4_t z; z[0] = 0.f; z[1] = 0.f; z[2] = 0.f; z[3] = 0.f;
#pragma unroll
  for (int m = 0; m < 8; ++m)
#pragma unroll
    for (int n = 0; n < 4; ++n) acc[m][n] = z;
  f32x4_t breg[4];

  // read-side bases: row byte = row*128; slot term = ((lane>>4)^(lane&7))*16
  // (row&7 == lane&7 for all frags). ks1 toggles addr bit6 (XOR 64).
  const uint32_t lbase = (uint32_t)(size_t)&lds[0];
  const uint32_t slotB = (uint32_t)(((lane >> 4) ^ (lane & 7)) & 7) * 16;
  const uint32_t aBase = lbase + (uint32_t)(wr * 16384 + (lane & 15) * 128) + slotB;
  const uint32_t bBase = lbase + 32768 + (uint32_t)(wc * 8192 + (lane & 15) * 128) + slotB;

  // prologue: S0 B-h0(kt0) S1 A-h0 S2 A-h1 S3 B-h1 S4 B-h0(kt1)
  glds16(Bg + boffs[0][0], ldsc + 32768 + w * 1024);
  glds16(Bg + boffs[0][1], ldsc + 32768 + 8192 + w * 1024);
  glds16(Ag + aoffs[0][0], ldsc + 0 + w * 1024);
  glds16(Ag + aoffs[0][1], ldsc + 8192 + w * 1024);
  glds16(Ag + aoffs[1][0], ldsc + 16384 + w * 1024);
  glds16(Ag + aoffs[1][1], ldsc + 16384 + 8192 + w * 1024);
  glds16(Bg + boffs[1][0], ldsc + 49152 + w * 1024);
  glds16(Bg + boffs[1][1], ldsc + 49152 + 8192 + w * 1024);
  {
    uint32_t kb1 = 128;  // kt1 (NKT >= 2 always here)
    glds16(Bg + boffs[0][0] + kb1, ldsc + 65536 + 32768 + w * 1024);
    glds16(Bg + boffs[0][1] + kb1, ldsc + 65536 + 32768 + 8192 + w * 1024);
  }
  asm volatile("s_waitcnt vmcnt(2)" ::: "memory");
  __builtin_amdgcn_s_barrier();

  for (int i = 0; i < NIT; ++i) {
    int kA = 2 * i + 1; if (kA > NKT - 1) kA = NKT - 1;
    int kB = 2 * i + 2; if (kB > NKT - 1) kB = NKT - 1;
    int kC = 2 * i + 3; if (kC > NKT - 1) kC = NKT - 1;
    const uint32_t kbA = (uint32_t)kA * 128, kbB = (uint32_t)kB * 128, kbC = (uint32_t)kC * 128;
    phase_fn<0, 0,     65536 + 0,     1, 0, 0>(aBase, bBase, acc, breg, Ag, Bg, aoffs, boffs, kbA, ldsc, w);
    phase_fn<1, 0,     65536 + 16384, 1, 1, 0>(aBase, bBase, acc, breg, Ag, Bg, aoffs, boffs, kbA, ldsc, w);
    phase_fn<2, 0,     65536 + 49152, 0, 1, 0>(aBase, bBase, acc, breg, Ag, Bg, aoffs, boffs, kbA, ldsc, w);
    phase_fn<3, 0,     32768,         0, 0, 1>(aBase, bBase, acc, breg, Ag, Bg, aoffs, boffs, kbB, ldsc, w);
    phase_fn<0, 65536, 0,             1, 0, 0>(aBase, bBase, acc, breg, Ag, Bg, aoffs, boffs, kbB, ldsc, w);
    phase_fn<1, 65536, 16384,         1, 1, 0>(aBase, bBase, acc, breg, Ag, Bg, aoffs, boffs, kbB, ldsc, w);
    phase_fn<2, 65536, 49152,         0, 1, 0>(aBase, bBase, acc, breg, Ag, Bg, aoffs, boffs, kbB, ldsc, w);
    phase_fn<3, 65536, 65536 + 32768, 0, 0, 1>(aBase, bBase, acc, breg, Ag, Bg, aoffs, boffs, kbC, ldsc, w);
  }
  asm volatile("s_waitcnt vmcnt(0)" ::: "memory");  // drain before LDS reuse/exit

  // epilogue: C/D mapping col=lane&15, row=(lane>>4)*4+i2
  const int cb = nb * 256 + wc * 64;
  if constexpr (MODE == 1) {
#pragma unroll
    for (int M = 0; M < 8; ++M) {
      int pr = pos0 + wr * 128 + M * 16 + ((lane >> 4) << 2);
#pragma unroll
      for (int i2 = 0; i2 < 4; ++i2) {
        int pos = pr + i2;
        if (pos < vend) {
#pragma unroll
          for (int n = 0; n < 4; ++n) {
            int col = cb + n * 16 + (lane & 15);
            float v = acc[M][n][i2] + bias[e * ND + col];
            hout[(size_t)pos * ND + col] = f2b(fmaxf(v, 0.f));
          }
        }
      }
    }
  } else {
#pragma unroll
    for (int M = 0; M < 8; ++M) {
      int pr = pos0 + wr * 128 + M * 16 + ((lane >> 4) << 2);
#pragma unroll
      for (int i2 = 0; i2 < 4; ++i2) {
        int pos = pr + i2;
        if (pos < vend) {
          int bi = row_index[pos];
          float wgt = row_w[pos];
          float* orow = out + (size_t)bi * ND;
#pragma unroll
          for (int n = 0; n < 4; ++n) {
            int col = cb + n * 16 + (lane & 15);
            float bterm = (ks == 0) ? bias[e * ND + col] : 0.f;
            atomicAdd(orow + col, (acc[M][n][i2] + bterm) * wgt);
          }
        }
      }
    }
  }
}

extern "C" void kernel_launch(void* const* d_in, const int* in_sizes, int n_in,
                              void* d_out, int out_size, void* d_ws, size_t ws_size,
                              hipStream_t stream) {
  const float* x  = (const float*)d_in[0];   // [4096,1024]
  const float* Wg = (const float*)d_in[1];   // [1024,8]
  const float* bg = (const float*)d_in[2];   // [8]
  const float* W1 = (const float*)d_in[3];   // [8,1024,4096]
  const float* b1 = (const float*)d_in[4];   // [8,4096]
  const float* W2 = (const float*)d_in[5];   // [8,4096,1024]
  const float* b2 = (const float*)d_in[6];   // [8,1024]
  float* out = (float*)d_out;                // [4096,1024]

  char* ws = (char*)d_ws;
  uint16_t* w1t = (uint16_t*)ws; ws += (size_t)8 * 4096 * 1024 * 2;  // [E][H][D] bf16
  uint16_t* w2t = (uint16_t*)ws; ws += (size_t)8 * 1024 * 4096 * 2;  // [E][O][H] bf16
  uint16_t* xb  = (uint16_t*)ws; ws += (size_t)4096 * 1024 * 2;      // [B][D] bf16
  uint16_t* h   = (uint16_t*)ws; ws += (size_t)8192 * 4096 * 2;      // [8192][H] bf16
  int*   gidx = (int*)ws;   ws += 8192 * 4;
  float* gw   = (float*)ws; ws += 8192 * 4;
  int*   rix  = (int*)ws;   ws += 8192 * 4;
  float* rw   = (float*)ws; ws += 8192 * 4;
  int*   meta = (int*)ws;   ws += 4096;

  hipFuncSetAttribute((const void*)moe_gemm8<1024, 4096, 1, 1>,
                      hipFuncAttributeMaxDynamicSharedMemorySize, 131072);
  hipFuncSetAttribute((const void*)moe_gemm8<4096, 1024, 2, 2>,
                      hipFuncAttributeMaxDynamicSharedMemorySize, 131072);

  hipMemsetAsync(d_out, 0, (size_t)4096 * 1024 * 4, stream);
  moe_cvtx<<<4096, 256, 0, stream>>>(x, xb);
  moe_transpose<<<dim3(4096 / 64, 1024 / 64, 8), 256, 0, stream>>>(W1, w1t, 1024, 4096);
  moe_transpose<<<dim3(1024 / 64, 4096 / 64, 8), 256, 0, stream>>>(W2, w2t, 4096, 1024);
  moe_gate<<<1024, 256, 0, stream>>>(x, Wg, bg, gidx, gw);
  moe_scan<<<1, 256, 0, stream>>>(gidx, meta);
  moe_scatter<<<32, 256, 0, stream>>>(gidx, gw, meta, rix, rw);
  // GEMM1: 16 nb * 40 ty = 640 blocks; GEMM2: 4 nb * 2 ks * 40 ty = 320
  moe_gemm8<1024, 4096, 1, 1><<<dim3(16 * MAXT), 512, 131072, stream>>>(
      xb, w1t, b1, meta, rix, rw, h, nullptr);
  moe_gemm8<4096, 1024, 2, 2><<<dim3(4 * 2 * MAXT), 512, 131072, stream>>>(
      h, w2t, b2, meta, rix, rw, nullptr, out);
}